// Round 10
// baseline (23704.718 us; speedup 1.0000x reference)
//
#include <hip/hip_runtime.h>

// Problem constants
#define BB   64      // batch
#define TT   256     // seq len
#define II   768     // input dim
#define HH   384     // hidden per direction
#define DD   768     // 2*HH
#define G3   1152    // 3*HH
#define G6   2304    // both directions' gates

#define TILE 128
#define BK   16

typedef unsigned long long u64t;
typedef __attribute__((ext_vector_type(4))) float f32x4;

// ---------------------------------------------------------------------------
// GEMM: gx[t][bg=8][n=2304][b8=8] = bias[n] + sum_k X[t,b,k] * W[n,k]
// XCD-sliced output: group x streams its contiguous [n][8] slice.
// xmode 0: X = Sentences [B][T][768]; xmode 1: X = [T*B][768] row-major.
// ---------------------------------------------------------------------------
__global__ __launch_bounds__(256) void gemm_gx(
    const float* __restrict__ X, int xmode,
    const float* __restrict__ wf, const float* __restrict__ wb,
    const float* __restrict__ bif, const float* __restrict__ bib,
    float* __restrict__ gx)
{
    __shared__ float As[BK][TILE + 4];
    __shared__ float Bs[BK][TILE + 4];
    const int tid = threadIdx.x;
    const int tx = tid & 15, ty = tid >> 4;
    const int m0 = blockIdx.y * TILE;
    const int n0 = blockIdx.x * TILE;

    float acc[8][8];
#pragma unroll
    for (int i = 0; i < 8; i++)
#pragma unroll
        for (int j = 0; j < 8; j++) acc[i][j] = 0.f;

    for (int k0 = 0; k0 < 768; k0 += BK) {
#pragma unroll
        for (int l = 0; l < 2; l++) {
            int id = tid + l * 256;          // 0..511
            int r  = id >> 2;                // 0..127
            int kq = (id & 3) * 4;
            int m  = m0 + r;
            const float* src;
            if (xmode == 0) {
                int b = m & 63, t = m >> 6;
                src = X + (size_t)b * (TT * II) + (size_t)t * II + k0 + kq;
            } else {
                src = X + (size_t)m * 768 + k0 + kq;
            }
            float4 v = *(const float4*)src;
            As[kq + 0][r] = v.x; As[kq + 1][r] = v.y;
            As[kq + 2][r] = v.z; As[kq + 3][r] = v.w;
        }
#pragma unroll
        for (int l = 0; l < 2; l++) {
            int id = tid + l * 256;
            int r  = id >> 2;
            int kq = (id & 3) * 4;
            int n  = n0 + r;
            const float* wsrc = (n < G3) ? (wf + (size_t)n * 768)
                                         : (wb + (size_t)(n - G3) * 768);
            float4 v = *(const float4*)(wsrc + k0 + kq);
            Bs[kq + 0][r] = v.x; Bs[kq + 1][r] = v.y;
            Bs[kq + 2][r] = v.z; Bs[kq + 3][r] = v.w;
        }
        __syncthreads();
#pragma unroll
        for (int kk = 0; kk < BK; ++kk) {
            float av[8], bv[8];
            *(float4*)&av[0] = *(const float4*)&As[kk][ty * 8];
            *(float4*)&av[4] = *(const float4*)&As[kk][ty * 8 + 4];
            *(float4*)&bv[0] = *(const float4*)&Bs[kk][tx * 8];
            *(float4*)&bv[4] = *(const float4*)&Bs[kk][tx * 8 + 4];
#pragma unroll
            for (int i = 0; i < 8; i++)
#pragma unroll
                for (int j = 0; j < 8; j++)
                    acc[i][j] = fmaf(av[i], bv[j], acc[i][j]);
        }
        __syncthreads();
    }

#pragma unroll
    for (int i = 0; i < 8; i++) {
        int m = m0 + ty * 8 + i;
        int t = m >> 6, b = m & 63;
        int bg = b >> 3, b8 = b & 7;
        float* dst = gx + (((size_t)t * 8 + bg) * G6 + n0 + tx * 8) * 8 + b8;
#pragma unroll
        for (int j = 0; j < 8; j++) {
            int n = n0 + tx * 8 + j;
            float bias = (n < G3) ? bif[n] : bib[n - G3];
            dst[(size_t)j * 8] = acc[i][j] + bias;
        }
    }
}

// ---------------------------------------------------------------------------
// Recurrent kernel v11: batch-partitioned across XCDs, dual-published
// mantissa-tagged h, sticky L3-mirror fallback. No barriers, no detection,
// no unbounded local spin -> cannot hang, correct for any WG placement.
//
// 256 WGs x 256 thr, 1/CU (117 KB LDS of weights). Group x = bid&7 handles
// batch rows 8x..8x+7. j=bid>>3: dir=j&1, 24 columns c0=(j>>1)*24 per WG.
// Wave w: cols c0+6w..+5; lane: b=lane>>3 (batch), ks=lane&7 (k-slice of 48).
// Per step: spin-load own dir's h[8][384] slice (12 dwordx4 sc0 from local
// L2 buffer; fallback sc0 sc1 from L3 mirror), 864 fma/lane from LDS
// weights, 3-hop shfl k-reduce, ks==0 lanes do gate math and dual-publish
// tagged dwords. Tags: low 8 mantissa bits = step+1 (rel err <= 2^-15,
// proven 4.9e-4 absmax in v10). Ping-pong race-freedom as v5/v10.
// ---------------------------------------------------------------------------

#define HLOAD(SCB) \
    asm volatile( \
        "global_load_dwordx4 %0,  %12, off " SCB "\n\t" \
        "global_load_dwordx4 %1,  %12, off offset:16 " SCB "\n\t" \
        "global_load_dwordx4 %2,  %12, off offset:32 " SCB "\n\t" \
        "global_load_dwordx4 %3,  %12, off offset:48 " SCB "\n\t" \
        "global_load_dwordx4 %4,  %12, off offset:64 " SCB "\n\t" \
        "global_load_dwordx4 %5,  %12, off offset:80 " SCB "\n\t" \
        "global_load_dwordx4 %6,  %12, off offset:96 " SCB "\n\t" \
        "global_load_dwordx4 %7,  %12, off offset:112 " SCB "\n\t" \
        "global_load_dwordx4 %8,  %12, off offset:128 " SCB "\n\t" \
        "global_load_dwordx4 %9,  %12, off offset:144 " SCB "\n\t" \
        "global_load_dwordx4 %10, %12, off offset:160 " SCB "\n\t" \
        "global_load_dwordx4 %11, %12, off offset:176 " SCB "\n\t" \
        "s_waitcnt vmcnt(0)" \
        : "=&v"(F[0]), "=&v"(F[1]), "=&v"(F[2]),  "=&v"(F[3]), \
          "=&v"(F[4]), "=&v"(F[5]), "=&v"(F[6]),  "=&v"(F[7]), \
          "=&v"(F[8]), "=&v"(F[9]), "=&v"(F[10]), "=&v"(F[11]) \
        : "v"(hb) : "memory")

__global__ __launch_bounds__(256) void recur11(
    const float* __restrict__ gxT,  // [T][8][2304][8] (b_ih already added)
    const float* __restrict__ whf, const float* __restrict__ whb,
    const float* __restrict__ bhf, const float* __restrict__ bhb,
    unsigned* __restrict__ hl,      // local  [8x][2dir][2pp][8][384], zeroed
    unsigned* __restrict__ hm,      // mirror [8x][2dir][2pp][8][384], zeroed
    float* __restrict__ out)        // [T][B][768]
{
    extern __shared__ float wlds[];         // [72][8*52] = 119808 B

    const int bid  = blockIdx.x;            // 0..255
    const int x    = bid & 7;               // presumed XCD group
    const int j    = bid >> 3;              // 0..31
    const int dir  = j & 1;
    const int c0   = (j >> 1) * 24;         // 24 columns per WG
    const int tid  = threadIdx.x;
    const int w    = __builtin_amdgcn_readfirstlane(tid >> 6);  // wave 0..3
    const int lane = tid & 63;
    const int b    = lane >> 3;             // batch row within group
    const int ks   = lane & 7;              // k-slice (48 wide)
    const int c0w  = c0 + w * 6;            // this wave's 6 columns

    const float* wh = dir ? whb : whf;
    const float* bh = dir ? bhb : bhf;

    // ---- weights -> LDS, [row=cc*3+g][ks][52] padded (conflict-free)
    for (int i = tid; i < 72 * 96; i += 256) {
        int row = i / 96;                   // 0..71
        int kq  = (i % 96) * 4;             // 0..380
        int cc = row / 3, g = row % 3;
        float4 v = *(const float4*)(wh + (size_t)(g * HH + c0 + cc) * HH + kq);
        *(float4*)&wlds[row * 416 + (kq / 48) * 52 + (kq % 48)] = v;
    }
    __syncthreads();                        // only barrier in the kernel

    // biases for this wave's 6 columns
    float bR[6], bZ[6], bN[6];
#pragma unroll
    for (int q = 0; q < 6; q++) {
        bR[q] = bh[c0w + q];
        bZ[q] = bh[HH + c0w + q];
        bN[q] = bh[2 * HH + c0w + q];
    }

    unsigned* hlx = hl + ((size_t)x * 2 + dir) * 6144;   // [2pp][8][384]
    unsigned* hmx = hm + ((size_t)x * 2 + dir) * 6144;

    float hprev[6] = {0.f, 0.f, 0.f, 0.f, 0.f, 0.f};
    bool uloc = true;                        // sticky local-L2 fast path

#pragma unroll 1
    for (int s = 0; s < TT; ++s) {
        const int t  = dir ? (TT - 1 - s) : s;
        const int pp = s & 1, pn = pp ^ 1;
        const unsigned want8 = (unsigned)s & 0xFFu;
        const unsigned tagp  = (unsigned)(s + 1) & 0xFFu;

        // gx loads for finalize lanes (plain cached, issued before the spin)
        float gxr[6], gxz[6], gxn[6];
        if (ks == 0) {
            const float* gb = gxT + (((size_t)t * 8 + x) * G6 + dir * G3) * 8 + b;
#pragma unroll
            for (int q = 0; q < 6; q++) {
                int c = c0w + q;
                gxr[q] = gb[(size_t)(0 * HH + c) * 8];
                gxz[q] = gb[(size_t)(1 * HH + c) * 8];
                gxn[q] = gb[(size_t)(2 * HH + c) * 8];
            }
        }

        // ---- spin-load my h slice (self-validating tagged dwords)
        const unsigned* hlb = hlx + pp * 3072 + b * 384 + ks * 48;
        const unsigned* hmb = hmx + pp * 3072 + b * 384 + ks * 48;
        f32x4 F[12];
        int tries = 0;
        for (;;) {
            if (uloc) { const unsigned* hb = hlb; HLOAD("sc0"); }
            else      { const unsigned* hb = hmb; HLOAD("sc0 sc1"); }
            bool ok = true;
#pragma unroll
            for (int i2 = 0; i2 < 12; ++i2) {
                ok = ok && ((__float_as_uint(F[i2].x) & 0xFFu) == want8)
                        && ((__float_as_uint(F[i2].y) & 0xFFu) == want8)
                        && ((__float_as_uint(F[i2].z) & 0xFFu) == want8)
                        && ((__float_as_uint(F[i2].w) & 0xFFu) == want8);
            }
            if (__all(ok)) break;
            if (uloc && (++tries > 200)) uloc = false;   // sticky fallback
            __builtin_amdgcn_s_sleep(1);
        }

        // ---- 18 dot-partials over my 48 k-values (weights broadcast from LDS)
        float acc[18];
#pragma unroll
        for (int r = 0; r < 18; ++r) acc[r] = 0.f;
#pragma unroll
        for (int kk = 0; kk < 12; ++kk) {
            f32x4 hv = F[kk];
#pragma unroll
            for (int r = 0; r < 18; ++r) {
                const f32x4 wv =
                    *(const f32x4*)&wlds[(w * 18 + r) * 416 + ks * 52 + kk * 4];
                acc[r] = fmaf(hv.x, wv.x, acc[r]);
                acc[r] = fmaf(hv.y, wv.y, acc[r]);
                acc[r] = fmaf(hv.z, wv.z, acc[r]);
                acc[r] = fmaf(hv.w, wv.w, acc[r]);
            }
        }

        // ---- k-reduce over the 8 slices (3 shfl hops; result at ks==0)
#pragma unroll
        for (int r = 0; r < 18; ++r) {
            acc[r] += __shfl_down(acc[r], 4);
            acc[r] += __shfl_down(acc[r], 2);
            acc[r] += __shfl_down(acc[r], 1);
        }

        // ---- finalize + dual-publish (ks==0 lanes: one per batch row)
        if (ks == 0) {
            unsigned* hlp = hlx + pn * 3072 + b * 384;
            unsigned* hmp = hmx + pn * 3072 + b * 384;
            float*    op  = out + ((size_t)t * BB + x * 8 + b) * DD + dir * HH;
#pragma unroll
            for (int q = 0; q < 6; ++q) {
                float ghr = acc[q * 3 + 0] + bR[q];
                float ghz = acc[q * 3 + 1] + bZ[q];
                float ghn = acc[q * 3 + 2] + bN[q];
                float rr = 1.f / (1.f + expf(-(gxr[q] + ghr)));
                float zz = 1.f / (1.f + expf(-(gxz[q] + ghz)));
                float nn = tanhf(gxn[q] + rr * ghn);
                float hnew = (1.f - zz) * nn + zz * hprev[q];
                hprev[q] = hnew;

                unsigned bits = (__float_as_uint(hnew) & 0xFFFFFF00u) | tagp;
                // local (same-XCD L2) publish: plain store, L1 write-through
                __hip_atomic_store(hlp + c0w + q, bits, __ATOMIC_RELAXED,
                                   __HIP_MEMORY_SCOPE_WORKGROUP);
                // mirror (L3) publish: always, for fallback consumers
                __hip_atomic_store(hmp + c0w + q, bits, __ATOMIC_RELAXED,
                                   __HIP_MEMORY_SCOPE_AGENT);
                op[c0w + q] = hnew;
            }
        }
    }
}

// ---------------------------------------------------------------------------
// Attention logits: logits[b][t] += sum_n tanh(hidden[t,b,:]·fcw[n,:] + fcb[n]) * upw[n]
// ---------------------------------------------------------------------------
__global__ __launch_bounds__(256) void attn_logits(
    const float* __restrict__ Xh,   // hidden [T*B][768]
    const float* __restrict__ fcw,  // [768][768]
    const float* __restrict__ fcb, const float* __restrict__ upw,
    float* __restrict__ logits)     // [B][T]
{
    __shared__ float As[BK][TILE + 4];
    __shared__ float Bs[BK][TILE + 4];
    __shared__ float red[TILE][17];
    const int tid = threadIdx.x;
    const int tx = tid & 15, ty = tid >> 4;
    const int m0 = blockIdx.y * TILE;
    const int n0 = blockIdx.x * TILE;

    float acc[8][8];
#pragma unroll
    for (int i = 0; i < 8; i++)
#pragma unroll
        for (int j = 0; j < 8; j++) acc[i][j] = 0.f;

    for (int k0 = 0; k0 < 768; k0 += BK) {
#pragma unroll
        for (int l = 0; l < 2; l++) {
            int id = tid + l * 256;
            int r  = id >> 2;
            int kq = (id & 3) * 4;
            float4 v = *(const float4*)(Xh + (size_t)(m0 + r) * 768 + k0 + kq);
            As[kq + 0][r] = v.x; As[kq + 1][r] = v.y;
            As[kq + 2][r] = v.z; As[kq + 3][r] = v.w;
        }
#pragma unroll
        for (int l = 0; l < 2; l++) {
            int id = tid + l * 256;
            int r  = id >> 2;
            int kq = (id & 3) * 4;
            float4 v = *(const float4*)(fcw + (size_t)(n0 + r) * 768 + k0 + kq);
            Bs[kq + 0][r] = v.x; Bs[kq + 1][r] = v.y;
            Bs[kq + 2][r] = v.z; Bs[kq + 3][r] = v.w;
        }
        __syncthreads();
#pragma unroll
        for (int kk = 0; kk < BK; ++kk) {
            float av[8], bv[8];
            *(float4*)&av[0] = *(const float4*)&As[kk][ty * 8];
            *(float4*)&av[4] = *(const float4*)&As[kk][ty * 8 + 4];
            *(float4*)&bv[0] = *(const float4*)&Bs[kk][tx * 8];
            *(float4*)&bv[4] = *(const float4*)&Bs[kk][tx * 8 + 4];
#pragma unroll
            for (int i = 0; i < 8; i++)
#pragma unroll
                for (int j = 0; j < 8; j++)
                    acc[i][j] = fmaf(av[i], bv[j], acc[i][j]);
        }
        __syncthreads();
    }

#pragma unroll
    for (int i = 0; i < 8; i++) {
        float p = 0.f;
#pragma unroll
        for (int jj = 0; jj < 8; jj++) {
            int n = n0 + tx * 8 + jj;
            p += tanhf(acc[i][jj] + fcb[n]) * upw[n];
        }
        red[ty * 8 + i][tx] = p;
    }
    __syncthreads();
    if (tid < TILE) {
        float s = 0.f;
#pragma unroll
        for (int xk = 0; xk < 16; xk++) s += red[tid][xk];
        int m = m0 + tid;
        int t = m >> 6, b = m & 63;
        atomicAdd(&logits[(size_t)b * TT + t], s);
    }
}

// ---------------------------------------------------------------------------
// Softmax over T per batch + weighted pooling
// ---------------------------------------------------------------------------
__global__ __launch_bounds__(256) void softmax_pool(
    const float* __restrict__ logits, const float* __restrict__ upwb,
    const float* __restrict__ hidden, float* __restrict__ out)
{
    const int b = blockIdx.x, tid = threadIdx.x;
    __shared__ float sa[256];
    __shared__ float red[256];

    float l = logits[(size_t)b * TT + tid] + upwb[0];
    red[tid] = l; __syncthreads();
    for (int s = 128; s > 0; s >>= 1) {
        if (tid < s) red[tid] = fmaxf(red[tid], red[tid + s]);
        __syncthreads();
    }
    float mx = red[0];
    __syncthreads();
    float e = expf(l - mx);
    sa[tid] = e; red[tid] = e; __syncthreads();
    for (int s = 128; s > 0; s >>= 1) {
        if (tid < s) red[tid] += red[tid + s];
        __syncthreads();
    }
    float inv = 1.f / red[0];

    float o0 = 0.f, o1 = 0.f, o2 = 0.f;
    for (int t = 0; t < TT; t++) {
        float a = sa[t] * inv;
        const float* hp = hidden + (size_t)t * (BB * DD) + (size_t)b * DD;
        o0 = fmaf(a, hp[tid],       o0);
        o1 = fmaf(a, hp[tid + 256], o1);
        o2 = fmaf(a, hp[tid + 512], o2);
    }
    out[(size_t)b * DD + tid]       = o0;
    out[(size_t)b * DD + tid + 256] = o1;
    out[(size_t)b * DD + tid + 512] = o2;
}

// ---------------------------------------------------------------------------
extern "C" void kernel_launch(void* const* d_in, const int* in_sizes, int n_in,
                              void* d_out, int out_size, void* d_ws, size_t ws_size,
                              hipStream_t stream)
{
    const float* S        = (const float*)d_in[0];
    const float* w_ih_l0f = (const float*)d_in[1];
    const float* w_hh_l0f = (const float*)d_in[2];
    const float* b_ih_l0f = (const float*)d_in[3];
    const float* b_hh_l0f = (const float*)d_in[4];
    const float* w_ih_l0b = (const float*)d_in[5];
    const float* w_hh_l0b = (const float*)d_in[6];
    const float* b_ih_l0b = (const float*)d_in[7];
    const float* b_hh_l0b = (const float*)d_in[8];
    const float* w_ih_l1f = (const float*)d_in[9];
    const float* w_hh_l1f = (const float*)d_in[10];
    const float* b_ih_l1f = (const float*)d_in[11];
    const float* b_hh_l1f = (const float*)d_in[12];
    const float* w_ih_l1b = (const float*)d_in[13];
    const float* w_hh_l1b = (const float*)d_in[14];
    const float* b_ih_l1b = (const float*)d_in[15];
    const float* b_hh_l1b = (const float*)d_in[16];
    const float* fc_w     = (const float*)d_in[17];
    const float* fc_b     = (const float*)d_in[18];
    const float* upw_w    = (const float*)d_in[19];
    const float* upw_b    = (const float*)d_in[20];

    // workspace layout (floats)
    float* gxT     = (float*)d_ws;                       // 256*8*2304*8
    float* buf2    = gxT  + (size_t)TT * G6 * BB;        // 256*64*768
    unsigned* hl0  = (unsigned*)(buf2 + (size_t)TT * BB * DD);  // 98304 dw
    unsigned* hm0  = hl0 + 98304;                        // 98304 dw
    unsigned* hl1  = hm0 + 98304;                        // 98304 dw
    unsigned* hm1  = hl1 + 98304;                        // 98304 dw
    float* logits  = (float*)(hm1 + 98304);              // 16384

    const size_t LDSZ = 72 * 416 * sizeof(float);        // 119808 B

    // zero all h buffers + logits (contiguous), every launch
    hipMemsetAsync(hl0, 0, (size_t)(4 * 98304 + 16384) * 4, stream);

    // layer 0 input gates
    gemm_gx<<<dim3(18, 128), 256, 0, stream>>>(S, 0, w_ih_l0f, w_ih_l0b,
                                               b_ih_l0f, b_ih_l0b, gxT);
    // layer 0 recurrence -> buf2
    {
        void* args[] = {(void*)&gxT, (void*)&w_hh_l0f, (void*)&w_hh_l0b,
                        (void*)&b_hh_l0f, (void*)&b_hh_l0b, (void*)&hl0,
                        (void*)&hm0, (void*)&buf2};
        hipLaunchCooperativeKernel((const void*)recur11, dim3(256), dim3(256),
                                   args, LDSZ, stream);
    }
    // layer 1 input gates (from buf2)
    gemm_gx<<<dim3(18, 128), 256, 0, stream>>>(buf2, 1, w_ih_l1f, w_ih_l1b,
                                               b_ih_l1f, b_ih_l1b, gxT);
    // layer 1 recurrence -> buf2 (separate pre-zeroed h regions)
    {
        void* args[] = {(void*)&gxT, (void*)&w_hh_l1f, (void*)&w_hh_l1b,
                        (void*)&b_hh_l1f, (void*)&b_hh_l1b, (void*)&hl1,
                        (void*)&hm1, (void*)&buf2};
        hipLaunchCooperativeKernel((const void*)recur11, dim3(256), dim3(256),
                                   args, LDSZ, stream);
    }
    // attention logits + pooling
    attn_logits<<<dim3(6, 128), 256, 0, stream>>>(buf2, fc_w, fc_b, upw_w, logits);
    softmax_pool<<<64, 256, 0, stream>>>(logits, upw_b, buf2, (float*)d_out);
}

// Round 11
// 14295.360 us; speedup vs baseline: 1.6582x; 1.6582x over previous
//
#include <hip/hip_runtime.h>

// Problem constants
#define BB   64      // batch
#define TT   256     // seq len
#define II   768     // input dim
#define HH   384     // hidden per direction
#define DD   768     // 2*HH
#define G3   1152    // 3*HH
#define G6   2304    // both directions' gates

#define TILE 128
#define BK   16

// ---------------------------------------------------------------------------
// GEMM: gx[t][b][n] = bias[n] + sum_k X[t,b,k] * W[n,k]   (n in [0,2304))
// Natural layout (round-1 version): recurrence thread c reads n=c,c+384,...
// consecutively across threads -> coalesced.
// xmode 0: X = Sentences [B][T][768]; xmode 1: X = [T*B][768] row-major.
// ---------------------------------------------------------------------------
__global__ __launch_bounds__(256) void gemm_gx(
    const float* __restrict__ X, int xmode,
    const float* __restrict__ wf, const float* __restrict__ wb,
    const float* __restrict__ bif, const float* __restrict__ bib,
    float* __restrict__ gx)
{
    __shared__ float As[BK][TILE + 4];
    __shared__ float Bs[BK][TILE + 4];
    const int tid = threadIdx.x;
    const int tx = tid & 15, ty = tid >> 4;
    const int m0 = blockIdx.y * TILE;
    const int n0 = blockIdx.x * TILE;

    float acc[8][8];
#pragma unroll
    for (int i = 0; i < 8; i++)
#pragma unroll
        for (int j = 0; j < 8; j++) acc[i][j] = 0.f;

    for (int k0 = 0; k0 < 768; k0 += BK) {
#pragma unroll
        for (int l = 0; l < 2; l++) {
            int id = tid + l * 256;          // 0..511
            int r  = id >> 2;                // 0..127
            int kq = (id & 3) * 4;
            int m  = m0 + r;
            const float* src;
            if (xmode == 0) {
                int b = m & 63, t = m >> 6;
                src = X + (size_t)b * (TT * II) + (size_t)t * II + k0 + kq;
            } else {
                src = X + (size_t)m * 768 + k0 + kq;
            }
            float4 v = *(const float4*)src;
            As[kq + 0][r] = v.x; As[kq + 1][r] = v.y;
            As[kq + 2][r] = v.z; As[kq + 3][r] = v.w;
        }
#pragma unroll
        for (int l = 0; l < 2; l++) {
            int id = tid + l * 256;
            int r  = id >> 2;
            int kq = (id & 3) * 4;
            int n  = n0 + r;
            const float* wsrc = (n < G3) ? (wf + (size_t)n * 768)
                                         : (wb + (size_t)(n - G3) * 768);
            float4 v = *(const float4*)(wsrc + k0 + kq);
            Bs[kq + 0][r] = v.x; Bs[kq + 1][r] = v.y;
            Bs[kq + 2][r] = v.z; Bs[kq + 3][r] = v.w;
        }
        __syncthreads();
#pragma unroll
        for (int kk = 0; kk < BK; ++kk) {
            float av[8], bv[8];
            *(float4*)&av[0] = *(const float4*)&As[kk][ty * 8];
            *(float4*)&av[4] = *(const float4*)&As[kk][ty * 8 + 4];
            *(float4*)&bv[0] = *(const float4*)&Bs[kk][tx * 8];
            *(float4*)&bv[4] = *(const float4*)&Bs[kk][tx * 8 + 4];
#pragma unroll
            for (int i = 0; i < 8; i++)
#pragma unroll
                for (int j = 0; j < 8; j++)
                    acc[i][j] = fmaf(av[i], bv[j], acc[i][j]);
        }
        __syncthreads();
    }

#pragma unroll
    for (int i = 0; i < 8; i++) {
        int m = m0 + ty * 8 + i;
        int t = m >> 6, b = m & 63;
        float* dst = gx + (size_t)t * (BB * G6) + (size_t)b * G6 + n0 + tx * 8;
#pragma unroll
        for (int j = 0; j < 8; j++) {
            int n = n0 + tx * 8 + j;
            float bias = (n < G3) ? bif[n] : bib[n - G3];
            dst[j] = acc[i][j] + bias;
        }
    }
}

// ---------------------------------------------------------------------------
// prep_w: pack w_hh fp32 [1152][384] -> bf16-pair u32 array, per-thread-
// contiguous layout wpk[c=384][blk=24][g=3][u=8], u32 = (bf16(w[g*384+c][k]),
// bf16(w[..][k+1])<<16), k = blk*16 + u*2. RTNE rounding.
// ---------------------------------------------------------------------------
__global__ __launch_bounds__(256) void prep_w(
    const float* __restrict__ w0f, const float* __restrict__ w0b,
    const float* __restrict__ w1f, const float* __restrict__ w1b,
    unsigned* __restrict__ p0f, unsigned* __restrict__ p0b,
    unsigned* __restrict__ p1f, unsigned* __restrict__ p1b)
{
    const int m = blockIdx.y;
    const float* src = (m == 0) ? w0f : (m == 1) ? w0b : (m == 2) ? w1f : w1b;
    unsigned*    dst = (m == 0) ? p0f : (m == 1) ? p0b : (m == 2) ? p1f : p1b;
    int i = blockIdx.x * 256 + threadIdx.x;
    if (i >= 384 * 576) return;
    int c   = i / 576, r = i % 576;
    int blk = r / 24;
    int g   = (r % 24) / 8;
    int u   = r % 8;
    int k   = blk * 16 + u * 2;
    int row = g * HH + c;
    unsigned a0 = __float_as_uint(src[(size_t)row * HH + k]);
    unsigned a1 = __float_as_uint(src[(size_t)row * HH + k + 1]);
    a0 = (a0 + 0x7FFFu + ((a0 >> 16) & 1u)) >> 16;   // RTNE to bf16
    a1 = (a1 + 0x7FFFu + ((a1 >> 16) & 1u)) >> 16;
    dst[i] = a0 | (a1 << 16);
}

// ---------------------------------------------------------------------------
// Recurrent kernel v12: ZERO inter-WG communication.
// 64 WGs x 384 threads. WG = (dir = bid&1, batch rows {2*(bid>>1), +1}).
// Thread c owns hidden column c: computes its 3 gate dots for both rows
// (weights stream from L2 as packed bf16 pairs), gate math, writes h to
// double-buffered LDS. One intra-CU __syncthreads per step. h never leaves
// the CU. No spins, no flags, no cooperative launch.
// ---------------------------------------------------------------------------
__device__ __forceinline__ void acc4(unsigned w, float2 p, float2 q,
                                     float& ax, float& ay,
                                     float& bx, float& by)
{
    float wl = __uint_as_float(w << 16);          // bf16 -> f32 (k)
    float wh = __uint_as_float(w & 0xFFFF0000u);  // (k+1)
    ax = fmaf(wl, p.x, ax); ay = fmaf(wh, p.y, ay);
    bx = fmaf(wl, q.x, bx); by = fmaf(wh, q.y, by);
}

__global__ __launch_bounds__(384) void recur12(
    const float* __restrict__ gx,   // [T][B][2304] (b_ih already added)
    const unsigned* __restrict__ wpf, const unsigned* __restrict__ wpb,
    const float* __restrict__ bhf, const float* __restrict__ bhb,
    float* __restrict__ out)        // [T][B][768]
{
    __shared__ float hbuf[2][2][HH];        // [pp][row][col], 6 KB

    const int bid = blockIdx.x;             // 0..63
    const int dir = bid & 1;
    const int b0  = (bid >> 1) * 2;         // this WG's 2 batch rows
    const int c   = threadIdx.x;            // 0..383: my hidden column

    const unsigned* wc = (dir ? wpb : wpf) + (size_t)c * 576;
    const float* bh = dir ? bhb : bhf;
    const float bhr = bh[c], bhz = bh[HH + c], bhn = bh[2 * HH + c];

    hbuf[0][0][c] = 0.f;
    hbuf[0][1][c] = 0.f;
    float hp0 = 0.f, hp1 = 0.f;
    __syncthreads();

#pragma unroll 1
    for (int s = 0; s < TT; ++s) {
        const int t  = dir ? (TT - 1 - s) : s;
        const int pp = s & 1, pn = pp ^ 1;

        // gx for my column, both rows (coalesced across threads)
        const float* g0 = gx + ((size_t)t * BB + b0) * G6 + dir * G3 + c;
        float gr0 = g0[0], gz0 = g0[HH], gn0 = g0[2 * HH];
        const float* g1 = g0 + G6;
        float gr1 = g1[0], gz1 = g1[HH], gn1 = g1[2 * HH];

        // 12 accumulators: (3 gates x 2 k-phases) x 2 rows
        float arx = 0.f, ary = 0.f, azx = 0.f, azy = 0.f, anx = 0.f, any2 = 0.f;
        float brx = 0.f, bry = 0.f, bzx = 0.f, bzy = 0.f, bnx = 0.f, bny2 = 0.f;

#pragma unroll 2
        for (int blk = 0; blk < 24; ++blk) {
            const uint4* wv = (const uint4*)(wc + blk * 24);
            uint4 wrA = wv[0], wrB = wv[1];     // gate r, u 0..7
            uint4 wzA = wv[2], wzB = wv[3];     // gate z
            uint4 wnA = wv[4], wnB = wv[5];     // gate n
            unsigned wr[8] = {wrA.x, wrA.y, wrA.z, wrA.w, wrB.x, wrB.y, wrB.z, wrB.w};
            unsigned wz[8] = {wzA.x, wzA.y, wzA.z, wzA.w, wzB.x, wzB.y, wzB.z, wzB.w};
            unsigned wn[8] = {wnA.x, wnA.y, wnA.z, wnA.w, wnB.x, wnB.y, wnB.z, wnB.w};

            const float2* H0 = (const float2*)&hbuf[pp][0][blk * 16];
            const float2* H1 = (const float2*)&hbuf[pp][1][blk * 16];
            float2 h0[8], h1[8];
#pragma unroll
            for (int j = 0; j < 8; ++j) { h0[j] = H0[j]; h1[j] = H1[j]; }

#pragma unroll
            for (int j = 0; j < 8; ++j) {
                acc4(wr[j], h0[j], h1[j], arx, ary, brx, bry);
                acc4(wz[j], h0[j], h1[j], azx, azy, bzx, bzy);
                acc4(wn[j], h0[j], h1[j], anx, any2, bnx, bny2);
            }
        }

        // gate math, row b0
        float ghr0 = arx + ary + bhr, ghz0 = azx + azy + bhz, ghn0 = anx + any2 + bhn;
        float r0 = 1.f / (1.f + expf(-(gr0 + ghr0)));
        float z0 = 1.f / (1.f + expf(-(gz0 + ghz0)));
        float n0 = tanhf(gn0 + r0 * ghn0);
        float h0n = (1.f - z0) * n0 + z0 * hp0;
        hp0 = h0n;
        // row b0+1
        float ghr1 = brx + bry + bhr, ghz1 = bzx + bzy + bhz, ghn1 = bnx + bny2 + bhn;
        float r1 = 1.f / (1.f + expf(-(gr1 + ghr1)));
        float z1 = 1.f / (1.f + expf(-(gz1 + ghz1)));
        float n1 = tanhf(gn1 + r1 * ghn1);
        float h1n = (1.f - z1) * n1 + z1 * hp1;
        hp1 = h1n;

        hbuf[pn][0][c] = h0n;
        hbuf[pn][1][c] = h1n;
        out[((size_t)t * BB + b0) * DD + dir * HH + c]     = h0n;
        out[((size_t)t * BB + b0 + 1) * DD + dir * HH + c] = h1n;

        __syncthreads();   // all reads of hbuf[pp] done; hbuf[pn] complete
    }
}

// ---------------------------------------------------------------------------
// Attention logits: logits[b][t] += sum_n tanh(hidden[t,b,:]·fcw[n,:] + fcb[n]) * upw[n]
// ---------------------------------------------------------------------------
__global__ __launch_bounds__(256) void attn_logits(
    const float* __restrict__ Xh,   // hidden [T*B][768]
    const float* __restrict__ fcw,  // [768][768]
    const float* __restrict__ fcb, const float* __restrict__ upw,
    float* __restrict__ logits)     // [B][T]
{
    __shared__ float As[BK][TILE + 4];
    __shared__ float Bs[BK][TILE + 4];
    __shared__ float red[TILE][17];
    const int tid = threadIdx.x;
    const int tx = tid & 15, ty = tid >> 4;
    const int m0 = blockIdx.y * TILE;
    const int n0 = blockIdx.x * TILE;

    float acc[8][8];
#pragma unroll
    for (int i = 0; i < 8; i++)
#pragma unroll
        for (int j = 0; j < 8; j++) acc[i][j] = 0.f;

    for (int k0 = 0; k0 < 768; k0 += BK) {
#pragma unroll
        for (int l = 0; l < 2; l++) {
            int id = tid + l * 256;
            int r  = id >> 2;
            int kq = (id & 3) * 4;
            float4 v = *(const float4*)(Xh + (size_t)(m0 + r) * 768 + k0 + kq);
            As[kq + 0][r] = v.x; As[kq + 1][r] = v.y;
            As[kq + 2][r] = v.z; As[kq + 3][r] = v.w;
        }
#pragma unroll
        for (int l = 0; l < 2; l++) {
            int id = tid + l * 256;
            int r  = id >> 2;
            int kq = (id & 3) * 4;
            float4 v = *(const float4*)(fcw + (size_t)(n0 + r) * 768 + k0 + kq);
            Bs[kq + 0][r] = v.x; Bs[kq + 1][r] = v.y;
            Bs[kq + 2][r] = v.z; Bs[kq + 3][r] = v.w;
        }
        __syncthreads();
#pragma unroll
        for (int kk = 0; kk < BK; ++kk) {
            float av[8], bv[8];
            *(float4*)&av[0] = *(const float4*)&As[kk][ty * 8];
            *(float4*)&av[4] = *(const float4*)&As[kk][ty * 8 + 4];
            *(float4*)&bv[0] = *(const float4*)&Bs[kk][tx * 8];
            *(float4*)&bv[4] = *(const float4*)&Bs[kk][tx * 8 + 4];
#pragma unroll
            for (int i = 0; i < 8; i++)
#pragma unroll
                for (int j = 0; j < 8; j++)
                    acc[i][j] = fmaf(av[i], bv[j], acc[i][j]);
        }
        __syncthreads();
    }

#pragma unroll
    for (int i = 0; i < 8; i++) {
        float p = 0.f;
#pragma unroll
        for (int jj = 0; jj < 8; jj++) {
            int n = n0 + tx * 8 + jj;
            p += tanhf(acc[i][jj] + fcb[n]) * upw[n];
        }
        red[ty * 8 + i][tx] = p;
    }
    __syncthreads();
    if (tid < TILE) {
        float s = 0.f;
#pragma unroll
        for (int xk = 0; xk < 16; xk++) s += red[tid][xk];
        int m = m0 + tid;
        int t = m >> 6, b = m & 63;
        atomicAdd(&logits[(size_t)b * TT + t], s);
    }
}

// ---------------------------------------------------------------------------
// Softmax over T per batch + weighted pooling
// ---------------------------------------------------------------------------
__global__ __launch_bounds__(256) void softmax_pool(
    const float* __restrict__ logits, const float* __restrict__ upwb,
    const float* __restrict__ hidden, float* __restrict__ out)
{
    const int b = blockIdx.x, tid = threadIdx.x;
    __shared__ float sa[256];
    __shared__ float red[256];

    float l = logits[(size_t)b * TT + tid] + upwb[0];
    red[tid] = l; __syncthreads();
    for (int s = 128; s > 0; s >>= 1) {
        if (tid < s) red[tid] = fmaxf(red[tid], red[tid + s]);
        __syncthreads();
    }
    float mx = red[0];
    __syncthreads();
    float e = expf(l - mx);
    sa[tid] = e; red[tid] = e; __syncthreads();
    for (int s = 128; s > 0; s >>= 1) {
        if (tid < s) red[tid] += red[tid + s];
        __syncthreads();
    }
    float inv = 1.f / red[0];

    float o0 = 0.f, o1 = 0.f, o2 = 0.f;
    for (int t = 0; t < TT; t++) {
        float a = sa[t] * inv;
        const float* hp = hidden + (size_t)t * (BB * DD) + (size_t)b * DD;
        o0 = fmaf(a, hp[tid],       o0);
        o1 = fmaf(a, hp[tid + 256], o1);
        o2 = fmaf(a, hp[tid + 512], o2);
    }
    out[(size_t)b * DD + tid]       = o0;
    out[(size_t)b * DD + tid + 256] = o1;
    out[(size_t)b * DD + tid + 512] = o2;
}

// ---------------------------------------------------------------------------
extern "C" void kernel_launch(void* const* d_in, const int* in_sizes, int n_in,
                              void* d_out, int out_size, void* d_ws, size_t ws_size,
                              hipStream_t stream)
{
    const float* S        = (const float*)d_in[0];
    const float* w_ih_l0f = (const float*)d_in[1];
    const float* w_hh_l0f = (const float*)d_in[2];
    const float* b_ih_l0f = (const float*)d_in[3];
    const float* b_hh_l0f = (const float*)d_in[4];
    const float* w_ih_l0b = (const float*)d_in[5];
    const float* w_hh_l0b = (const float*)d_in[6];
    const float* b_ih_l0b = (const float*)d_in[7];
    const float* b_hh_l0b = (const float*)d_in[8];
    const float* w_ih_l1f = (const float*)d_in[9];
    const float* w_hh_l1f = (const float*)d_in[10];
    const float* b_ih_l1f = (const float*)d_in[11];
    const float* b_hh_l1f = (const float*)d_in[12];
    const float* w_ih_l1b = (const float*)d_in[13];
    const float* w_hh_l1b = (const float*)d_in[14];
    const float* b_ih_l1b = (const float*)d_in[15];
    const float* b_hh_l1b = (const float*)d_in[16];
    const float* fc_w     = (const float*)d_in[17];
    const float* fc_b     = (const float*)d_in[18];
    const float* upw_w    = (const float*)d_in[19];
    const float* upw_b    = (const float*)d_in[20];

    // workspace layout
    float* gx      = (float*)d_ws;                       // 256*64*2304 f
    float* buf2    = gx   + (size_t)TT * BB * G6;        // 256*64*768 f
    unsigned* p0f  = (unsigned*)(buf2 + (size_t)TT * BB * DD);  // 221184 u32 each
    unsigned* p0b  = p0f + 221184;
    unsigned* p1f  = p0b + 221184;
    unsigned* p1b  = p1f + 221184;
    float* logits  = (float*)(p1b + 221184);             // 64*256 f

    // zero logits (attn uses atomicAdd)
    hipMemsetAsync(logits, 0, (size_t)BB * TT * sizeof(float), stream);

    // pack all 4 w_hh matrices to bf16 pairs (one-time, ~30 us)
    prep_w<<<dim3(864, 4), 256, 0, stream>>>(w_hh_l0f, w_hh_l0b, w_hh_l1f, w_hh_l1b,
                                             p0f, p0b, p1f, p1b);

    // layer 0 input gates
    gemm_gx<<<dim3(18, 128), 256, 0, stream>>>(S, 0, w_ih_l0f, w_ih_l0b,
                                               b_ih_l0f, b_ih_l0b, gx);
    // layer 0 recurrence -> buf2 (plain launch, independent WGs)
    recur12<<<64, 384, 0, stream>>>(gx, p0f, p0b, b_hh_l0f, b_hh_l0b, buf2);

    // layer 1 input gates (from buf2)
    gemm_gx<<<dim3(18, 128), 256, 0, stream>>>(buf2, 1, w_ih_l1f, w_ih_l1b,
                                               b_ih_l1f, b_ih_l1b, gx);
    // layer 1 recurrence -> buf2
    recur12<<<64, 384, 0, stream>>>(gx, p1f, p1b, b_hh_l1f, b_hh_l1b, buf2);

    // attention logits + pooling
    attn_logits<<<dim3(6, 128), 256, 0, stream>>>(buf2, fc_w, fc_b, upw_w, logits);
    softmax_pool<<<64, 256, 0, stream>>>(logits, upw_b, buf2, (float*)d_out);
}